// Round 10
// baseline (211.344 us; speedup 1.0000x reference)
//
#include <hip/hip_runtime.h>
#include <hip/hip_bf16.h>
#include <stdint.h>

// KANExpert: out[b,j] = sum_{i,g} basis(x[b,i])[g] * coeff[i,j,g] * scaling[i,j]
// == GEMM M=4096(batch) N=512(out) K=4096(=512 in_dim * 8 basis), bf16 MFMA.
//
// R12: R11 isolated the hoisted-read K-step: NULL (100.4 -> 101.2, noise).
// gemm_s is LDS-BW-bound (~96 KB LDS traffic per block-K-step; ~12-14us
// floor) -- further K-loop work is a deep rewrite, deferred. This round
// attacks the epilogue instead: fold the split-K reduction into the gemm
// with the threadfence-counter FINISHER pattern (no 3rd kernel):
//   every block: write P tile; __threadfence(); __syncthreads();
//   lane0: old = atomicAdd(cnt[mt*4+nt], 1); block with old==3 re-reads all
//   4 P tiles in fixed order ((P0+P1)+(P2+P3), bitwise == old reduce) and
//   writes out. No spinning -> no deadlock; device fences cover cross-XCD
//   visibility (G16). Counters re-zeroed by prep each call (ws is poisoned).
// Saves: 32 MiB reduce-read + launch gap (~8us predicted). K-loop untouched.
// Fill (~43us) is an unconditional harness charge on d_ws - untouchable.

#define BATCH   4096
#define IN_DIM  512
#define OUT_DIM 512
#define KDIM    (IN_DIM * 8)     // 4096
#define SPLITK  4
#define KSPAN   (KDIM / SPLITK)  // 1024 per block
#define NKS     (KSPAN / 64)     // 16 K-steps per block

typedef short short8 __attribute__((ext_vector_type(8)));
typedef float f32x4  __attribute__((ext_vector_type(4)));

// gfx9 s_waitcnt imm: vmcnt lo [3:0] hi [15:14], expcnt [6:4], lgkmcnt [11:8]
#define WAIT_VM8   0xF78    // vmcnt(8), lgkm/exp unconstrained
#define WAIT_VM0   0xF70    // vmcnt(0), lgkm/exp unconstrained
#define WAIT_LGKM0 0xC07F   // lgkmcnt(0), vm/exp unconstrained

// float -> bf16 bits, round-to-nearest-even
__device__ __forceinline__ unsigned short f2bf(float f) {
  union { float f; unsigned int u; } v; v.f = f;
  unsigned int r = v.u + 0x7FFFu + ((v.u >> 16) & 1u);
  return (unsigned short)(r >> 16);
}

// Uniform cubic B-spline window: x in [-1,1), h=0.4. m = floor((x+1)/h) in [0,4].
__device__ __forceinline__ void bspline_win(float xv, float* w, int* mm) {
  float t = (xv + 1.0f) * 2.5f;
  int m = (int)t;
  m = m < 0 ? 0 : (m > 4 ? 4 : m);
  float u  = t - (float)m;
  float u2 = u * u, u3 = u2 * u, om = 1.0f - u;
  w[0] = om * om * om * (1.0f / 6.0f);
  w[1] = (3.0f * u3 - 6.0f * u2 + 4.0f) * (1.0f / 6.0f);
  w[2] = (-3.0f * u3 + 3.0f * u2 + 3.0f * u + 1.0f) * (1.0f / 6.0f);
  w[3] = u3 * (1.0f / 6.0f);
  *mm = m;
}

__device__ __forceinline__ short8 basis_pack8(float xv) {
  float w[4]; int m;
  bspline_win(xv, w, &m);
  short8 h = {};
#pragma unroll
  for (int g = 0; g < 8; ++g) {
    int d = g - m + 3;
    float v = (d == 0) ? w[0] : (d == 1) ? w[1] : (d == 2) ? w[2] : (d == 3) ? w[3] : 0.0f;
    h[g] = (short)f2bf(v);
  }
  return h;
}

__device__ __forceinline__ void async_load16(const void* g, void* l) {
  __builtin_amdgcn_global_load_lds(
      (__attribute__((address_space(1))) void*)(uintptr_t)g,
      (__attribute__((address_space(3))) void*)(unsigned int)(uintptr_t)l,
      16, 0, 0);
}

// ---- precompute: basis + W^T pack + finisher-counter zero ---------------
__global__ void kan_prep(const float* __restrict__ x,
                         const float* __restrict__ coeff,
                         const float* __restrict__ scaling,
                         unsigned short* __restrict__ Ag,
                         unsigned short* __restrict__ Wt,
                         unsigned int* __restrict__ cnt) {
  const int b = blockIdx.x;
  const int NB_A = (BATCH * IN_DIM) / 256;      // 8192
  const int NB_W = (IN_DIM * OUT_DIM) / 256;    // 1024
  if (b < NB_A) {
    int idx = b * 256 + threadIdx.x;
    short8 h = basis_pack8(x[idx]);
    *reinterpret_cast<short8*>(Ag + (size_t)idx * 8) = h;
  } else if (b < NB_A + NB_W) {
    int idx = (b - NB_A) * 256 + threadIdx.x;   // i*512 + j
    int i = idx >> 9, j = idx & 511;
    float s = scaling[idx];
    const float4* cp = reinterpret_cast<const float4*>(coeff) + (size_t)idx * 2;
    float4 c0 = cp[0], c1 = cp[1];
    short8 h;
    h[0] = (short)f2bf(c0.x * s); h[1] = (short)f2bf(c0.y * s);
    h[2] = (short)f2bf(c0.z * s); h[3] = (short)f2bf(c0.w * s);
    h[4] = (short)f2bf(c1.x * s); h[5] = (short)f2bf(c1.y * s);
    h[6] = (short)f2bf(c1.z * s); h[7] = (short)f2bf(c1.w * s);
    *reinterpret_cast<short8*>(Wt + (size_t)j * KDIM + i * 8) = h;
  } else {
    // zero the 128 finisher counters (ws is re-poisoned every iteration)
    if (threadIdx.x < 128) cnt[threadIdx.x] = 0u;
  }
}

// ---- split-K 128x128x64 GEMM + in-kernel finisher reduction --------------
// K-loop identical to R11 (hoisted-read, measured 101us baseline).
// Epilogue: write P; fence; sync; lane0 atomicAdd(cnt); old==3 -> this block
// re-reads P0..P3 (fixed order) and writes out.
__global__ __launch_bounds__(256, 2)
void kan_gemm_s(const unsigned short* __restrict__ Ag,
                const unsigned short* __restrict__ Wt,
                float* __restrict__ Pt,
                unsigned int* __restrict__ cnt,
                float* __restrict__ out) {
  __shared__ unsigned short As[2][128 * 64];   // 2 x 16 KB
  __shared__ unsigned short Bs[2][128 * 64];   // 2 x 16 KB
  __shared__ unsigned int sArrive;

  const int tid  = threadIdx.x;
  const int lane = tid & 63;
  const int wid  = tid >> 6;
  const int wm = wid >> 1, wn = wid & 1;
  const int ln = lane & 15, quad = lane >> 4;

  const int b    = blockIdx.x;
  const int ks   = b & 3;
  const int mt   = (b >> 2) & 31;
  const int nt   = b >> 7;
  const int row0 = mt * 128;
  const int col0 = nt * 128;
  const int k0   = ks * KSPAN;

  f32x4 acc[4][4] = {};
  short8 af[2][4], bfr[2][4];                  // live across barrier (64 VGPR)

  const int lr = lane >> 3;                    // staging row within 8-row inst
  const int cg = (lane & 7) ^ lr;              // XOR-swizzled 16B chunk

  const unsigned short* aRow = Ag + (size_t)(row0 + wid * 32 + lr) * KDIM + k0 + cg * 8;
  const unsigned short* bRow = Wt + (size_t)(col0 + wid * 32 + lr) * KDIM + k0 + cg * 8;

  auto issue = [&](int kt, int st) {
    const int kk0 = kt * 64;
#pragma unroll
    for (int t = 0; t < 4; ++t) {
      const int rbase = wid * 32 + t * 8;                       // wave-uniform
      async_load16(aRow + (size_t)t * 8 * KDIM + kk0, &As[st][rbase * 64]);
      async_load16(bRow + (size_t)t * 8 * KDIM + kk0, &Bs[st][rbase * 64]);
    }
  };

  auto loadFrags = [&](int st) {
#pragma unroll
    for (int kk = 0; kk < 2; ++kk) {
#pragma unroll
      for (int m = 0; m < 4; ++m) {
        const int r    = wm * 64 + m * 16 + ln;
        const int slot = (kk * 4 + quad) ^ (r & 7);
        af[kk][m] = *reinterpret_cast<const short8*>(&As[st][r * 64 + slot * 8]);
      }
#pragma unroll
      for (int n = 0; n < 4; ++n) {
        const int c    = wn * 64 + n * 16 + ln;
        const int slot = (kk * 4 + quad) ^ (c & 7);
        bfr[kk][n] = *reinterpret_cast<const short8*>(&Bs[st][c * 64 + slot * 8]);
      }
    }
  };

  auto mfmaAll = [&]() {
#pragma unroll
    for (int kk = 0; kk < 2; ++kk)
#pragma unroll
      for (int m = 0; m < 4; ++m)
#pragma unroll
        for (int n = 0; n < 4; ++n)
          acc[m][n] = __builtin_amdgcn_mfma_f32_16x16x32_bf16(af[kk][m], bfr[kk][n], acc[m][n], 0, 0, 0);
  };

  issue(0, 0); issue(1, 1);

  for (int kt = 0; kt < NKS - 1; ++kt) {
    __builtin_amdgcn_s_waitcnt(WAIT_VM8);     // tile kt landed
    __builtin_amdgcn_s_barrier();
    loadFrags(kt & 1);                        // 16x ds_read_b128 -> regs
    __builtin_amdgcn_s_waitcnt(WAIT_LGKM0);   // our reads complete
    __builtin_amdgcn_sched_barrier(0);        // no motion across (rule 18)
    __builtin_amdgcn_s_barrier();             // all waves done reading stage
    if (kt + 2 < NKS) issue(kt + 2, kt & 1);  // recycle stage under MFMA phase
    mfmaAll();
  }
  __builtin_amdgcn_s_waitcnt(WAIT_VM0);       // last tile landed
  __builtin_amdgcn_s_barrier();
  loadFrags((NKS - 1) & 1);
  mfmaAll();

  // ---- write own partial tile (C/D layout: col = lane&15, row = quad*4+r)
  float* P = Pt + (size_t)ks * BATCH * OUT_DIM;
#pragma unroll
  for (int m = 0; m < 4; ++m)
#pragma unroll
    for (int n = 0; n < 4; ++n) {
      const int col = col0 + wn * 64 + n * 16 + ln;
#pragma unroll
      for (int r = 0; r < 4; ++r) {
        const int row = row0 + wm * 64 + m * 16 + quad * 4 + r;
        P[(size_t)row * OUT_DIM + col] = acc[m][n][r];
      }
    }

  // ---- finisher handshake (threadFenceReduction pattern) -----------------
  __threadfence();                 // release: P writes device-visible
  __syncthreads();                 // all threads' writes+fences done
  if (tid == 0) sArrive = atomicAdd(&cnt[mt * 4 + nt], 1u);
  __syncthreads();
  if (sArrive != 3u) return;       // not last -> done
  __threadfence();                 // acquire: see the other 3 blocks' P

  // last block for (mt,nt): out_tile = (P0+P1)+(P2+P3), fixed order
  const size_t Q = (size_t)BATCH * OUT_DIM / 4;          // float4 per partial
  const float4* p4 = reinterpret_cast<const float4*>(Pt);
#pragma unroll
  for (int q = 0; q < 16; ++q) {
    const int idx = q * 256 + tid;                       // 0..4095
    const int r   = idx >> 5;                            // row in tile
    const int c4  = idx & 31;                            // float4-col in tile
    const size_t e = (size_t)(row0 + r) * (OUT_DIM / 4) + (col0 >> 2) + c4;
    float4 a = p4[e], bb = p4[e + Q], c = p4[e + 2 * Q], d = p4[e + 3 * Q];
    float4 s;
    s.x = (a.x + bb.x) + (c.x + d.x);
    s.y = (a.y + bb.y) + (c.y + d.y);
    s.z = (a.z + bb.z) + (c.z + d.z);
    s.w = (a.w + bb.w) + (c.w + d.w);
    reinterpret_cast<float4*>(out)[e] = s;
  }
}

// ---- fallback (no ws): on-the-fly staging, 64-tile, direct store ---------
__global__ __launch_bounds__(256, 2)
void kan_gemm_fb(const float* __restrict__ x, const float* __restrict__ coeff,
                 const float* __restrict__ scaling, float* __restrict__ out) {
  __shared__ unsigned short As[64 * 64];
  __shared__ unsigned short Bs[64 * 64];

  const int tid  = threadIdx.x;
  const int lane = tid & 63;
  const int wid  = tid >> 6;
  const int wm = wid >> 1, wn = wid & 1;
  const int ln = lane & 15, quad = lane >> 4;
  const int row0 = blockIdx.y * 64;
  const int col0 = blockIdx.x * 64;

  f32x4 acc[2][2] = {};

  for (int kt = 0; kt < KDIM / 64; ++kt) {
#pragma unroll
    for (int pp = 0; pp < 2; ++pp) {
      const int p  = tid + pp * 256;
      const int rn = p & 63;
      const int il = p >> 6;
      const int sw = ((il ^ (rn & 7)) * 8);
      short8 ha = basis_pack8(x[(size_t)(row0 + rn) * IN_DIM + kt * 8 + il]);
      *reinterpret_cast<short8*>(&As[rn * 64 + sw]) = ha;
      const float* cbase = coeff + (size_t)(kt * 8 + il) * 4096 + (size_t)(col0 + rn) * 8;
      float4 c0 = reinterpret_cast<const float4*>(cbase)[0];
      float4 c1 = reinterpret_cast<const float4*>(cbase)[1];
      float s = scaling[(size_t)(kt * 8 + il) * OUT_DIM + col0 + rn];
      short8 hb;
      hb[0] = (short)f2bf(c0.x * s); hb[1] = (short)f2bf(c0.y * s);
      hb[2] = (short)f2bf(c0.z * s); hb[3] = (short)f2bf(c0.w * s);
      hb[4] = (short)f2bf(c1.x * s); hb[5] = (short)f2bf(c1.y * s);
      hb[6] = (short)f2bf(c1.z * s); hb[7] = (short)f2bf(c1.w * s);
      *reinterpret_cast<short8*>(&Bs[rn * 64 + sw]) = hb;
    }
    __syncthreads();
#pragma unroll
    for (int kk = 0; kk < 2; ++kk) {
      short8 a2[2], b2[2];
#pragma unroll
      for (int mt = 0; mt < 2; ++mt) {
        const int r  = wm * 32 + mt * 16 + ln;
        const int pc = (kk * 4 + quad) ^ (r & 7);
        a2[mt] = *reinterpret_cast<const short8*>(&As[r * 64 + pc * 8]);
      }
#pragma unroll
      for (int nt = 0; nt < 2; ++nt) {
        const int c  = wn * 32 + nt * 16 + ln;
        const int pc = (kk * 4 + quad) ^ (c & 7);
        b2[nt] = *reinterpret_cast<const short8*>(&Bs[c * 64 + pc * 8]);
      }
#pragma unroll
      for (int mt = 0; mt < 2; ++mt)
#pragma unroll
        for (int nt = 0; nt < 2; ++nt)
          acc[mt][nt] = __builtin_amdgcn_mfma_f32_16x16x32_bf16(a2[mt], b2[nt], acc[mt][nt], 0, 0, 0);
    }
    __syncthreads();
  }
#pragma unroll
  for (int mt = 0; mt < 2; ++mt)
#pragma unroll
    for (int nt = 0; nt < 2; ++nt) {
      const int col = col0 + wn * 32 + nt * 16 + ln;
#pragma unroll
      for (int r = 0; r < 4; ++r) {
        const int row = row0 + wm * 32 + mt * 16 + quad * 4 + r;
        out[(size_t)row * OUT_DIM + col] = acc[mt][nt][r];
      }
    }
}

// ---- launch ------------------------------------------------------------
extern "C" void kernel_launch(void* const* d_in, const int* in_sizes, int n_in,
                              void* d_out, int out_size, void* d_ws, size_t ws_size,
                              hipStream_t stream) {
  const float* x       = (const float*)d_in[0];
  const float* coeff   = (const float*)d_in[1];
  const float* scaling = (const float*)d_in[2];
  float* out = (float*)d_out;

  const size_t offW = (size_t)BATCH * KDIM * 2;            // Ag: 32 MB
  const size_t offP = offW + (size_t)OUT_DIM * KDIM * 2;   // Wt:  4 MB
  const size_t offC = offP + (size_t)SPLITK * BATCH * OUT_DIM * 4;  // P: 32 MB
  const size_t need = offC + 128 * sizeof(unsigned int);   // counters

  if (ws_size >= need) {
    unsigned short* Ag = (unsigned short*)d_ws;
    unsigned short* Wt = (unsigned short*)((char*)d_ws + offW);
    float*          Pt = (float*)((char*)d_ws + offP);
    unsigned int*  cnt = (unsigned int*)((char*)d_ws + offC);
    const int NB = (BATCH * IN_DIM) / 256 + (IN_DIM * OUT_DIM) / 256 + 1;
    kan_prep<<<NB, 256, 0, stream>>>(x, coeff, scaling, Ag, Wt, cnt);
    kan_gemm_s<<<(BATCH / 128) * (OUT_DIM / 128) * SPLITK, 256, 0, stream>>>(
        Ag, Wt, Pt, cnt, out);
  } else {
    kan_gemm_fb<<<dim3(OUT_DIM / 64, BATCH / 64), 256, 0, stream>>>(x, coeff, scaling, out);
  }
}

// Round 15
// 100.544 us; speedup vs baseline: 2.1020x; 2.1020x over previous
//
#include <hip/hip_runtime.h>
#include <hip/hip_bf16.h>
#include <stdint.h>

// KANExpert: out[b,j] = sum_{i,g} basis(x[b,i])[g] * coeff[i,j,g] * scaling[i,j]
// == GEMM M=4096(batch) N=512(out) K=4096(=512 in_dim * 8 basis), bf16 MFMA.
//
// R13 (5th submit; four broker timeouts): RESTORE the best-measured
// configuration (R0: 98.5us). Session ledger:
//   R0  prep(Ag,Wt in ws) + depth-3 ring 64x64 gemm, direct store:  98.5  <-- best
//   R3  scratch in __device__ globals (identical compute):         114.2  (ws is better)
//   R8  basis fused into gemm K-loop:                              146.7  (VALU serialization)
//   R9  split-K=4 128x128 + reduce kernel:                         100.4  (neutral)
//   R11 R9 + hoisted-read K-step:                                  101.2  (null)
//   R12 R11 + threadfence finisher reduction:                      211.3  (XCD fence tax)
// Conclusions baked in: (a) the 256MiB ws poison fill (~43us) is an
// unconditional harness charge - use ws freely; (b) cross-block reduction
// via atomics OR fences loses to streaming; (c) basis belongs in a BW-bound
// prep pass; (d) K-loop micro-scheduling (hoist/sched_barrier) is null at
// this size. Remaining headroom (~20us of gemm latency overhead) requires a
// deep-pipeline rewrite - not attempted here; this round re-anchors.

#define BATCH   4096
#define IN_DIM  512
#define OUT_DIM 512
#define KDIM    (IN_DIM * 8)   // 4096
#define NKT     (KDIM / 64)    // 64 K-tiles

typedef short short8 __attribute__((ext_vector_type(8)));
typedef float f32x4  __attribute__((ext_vector_type(4)));

// gfx9 s_waitcnt immediates: vmcnt low4 | expcnt<<4 | lgkmcnt<<8 (vmcnt hi @14)
#define WAIT_VM8 0xF78   // vmcnt(8), lgkm/exp unconstrained
#define WAIT_VM4 0xF74   // vmcnt(4)
#define WAIT_VM0 0xF70   // vmcnt(0)

// float -> bf16 bits, round-to-nearest-even
__device__ __forceinline__ unsigned short f2bf(float f) {
  union { float f; unsigned int u; } v; v.f = f;
  unsigned int r = v.u + 0x7FFFu + ((v.u >> 16) & 1u);
  return (unsigned short)(r >> 16);
}

// Uniform cubic B-spline window: x in [-1,1), h=0.4. m = floor((x+1)/h) in [0,4].
__device__ __forceinline__ void bspline_win(float xv, float* w, int* mm) {
  float t = (xv + 1.0f) * 2.5f;
  int m = (int)t;
  m = m < 0 ? 0 : (m > 4 ? 4 : m);
  float u  = t - (float)m;
  float u2 = u * u, u3 = u2 * u, om = 1.0f - u;
  w[0] = om * om * om * (1.0f / 6.0f);
  w[1] = (3.0f * u3 - 6.0f * u2 + 4.0f) * (1.0f / 6.0f);
  w[2] = (-3.0f * u3 + 3.0f * u2 + 3.0f * u + 1.0f) * (1.0f / 6.0f);
  w[3] = u3 * (1.0f / 6.0f);
  *mm = m;
}

__device__ __forceinline__ short8 basis_pack8(float xv) {
  float w[4]; int m;
  bspline_win(xv, w, &m);
  short8 h = {};
#pragma unroll
  for (int g = 0; g < 8; ++g) {
    int d = g - m + 3;
    float v = (d == 0) ? w[0] : (d == 1) ? w[1] : (d == 2) ? w[2] : (d == 3) ? w[3] : 0.0f;
    h[g] = (short)f2bf(v);
  }
  return h;
}

__device__ __forceinline__ void async_load16(const void* g, void* l) {
  __builtin_amdgcn_global_load_lds(
      (__attribute__((address_space(1))) void*)(uintptr_t)g,
      (__attribute__((address_space(3))) void*)(unsigned int)(uintptr_t)l,
      16, 0, 0);
}

// ---- fused precompute: basis (blocks 0..8191) + W^T pack (8192..9215) ----
__global__ void kan_prep(const float* __restrict__ x,
                         const float* __restrict__ coeff,
                         const float* __restrict__ scaling,
                         unsigned short* __restrict__ Ag,
                         unsigned short* __restrict__ Wt) {
  const int b = blockIdx.x;
  if (b < (BATCH * IN_DIM) / 256) {
    int idx = b * 256 + threadIdx.x;
    short8 h = basis_pack8(x[idx]);
    *reinterpret_cast<short8*>(Ag + (size_t)idx * 8) = h;
  } else {
    int idx = (b - (BATCH * IN_DIM) / 256) * 256 + threadIdx.x;  // i*512 + j
    int i = idx >> 9, j = idx & 511;
    float s = scaling[idx];
    const float4* cp = reinterpret_cast<const float4*>(coeff) + (size_t)idx * 2;
    float4 c0 = cp[0], c1 = cp[1];
    short8 h;
    h[0] = (short)f2bf(c0.x * s); h[1] = (short)f2bf(c0.y * s);
    h[2] = (short)f2bf(c0.z * s); h[3] = (short)f2bf(c0.w * s);
    h[4] = (short)f2bf(c1.x * s); h[5] = (short)f2bf(c1.y * s);
    h[6] = (short)f2bf(c1.z * s); h[7] = (short)f2bf(c1.w * s);
    *reinterpret_cast<short8*>(Wt + (size_t)j * KDIM + i * 8) = h;
  }
}

// ---- pipelined 64x64x64 GEMM, depth-3 LDS ring ---------------------------
// 256 thr = 4 waves (2x2), wave tile 32x32 (2x2 of 16x16x32). 1-D grid of
// 512 blocks: row-tile = b%64 (XCD = b%8 -> same-row blocks share one L2),
// col-tile = b/64. Protocol per iter k (stage st = k%3):
//   s_waitcnt vmcnt(8)  -- own 4 loads of tile k retired; k+1,k+2 in flight
//   s_barrier           -- all waves' tile-k loads retired
//   compute(st)
//   s_barrier           -- stage st free to recycle
//   issue tile k+3 -> st
__global__ __launch_bounds__(256, 2)
void kan_gemm_p(const unsigned short* __restrict__ Ag,
                const unsigned short* __restrict__ Wt,
                float* __restrict__ out) {
  __shared__ unsigned short As[3][64 * 64];   // 3 x 8 KB
  __shared__ unsigned short Bs[3][64 * 64];   // 3 x 8 KB

  const int tid  = threadIdx.x;
  const int lane = tid & 63;
  const int wid  = tid >> 6;
  const int wm = wid >> 1, wn = wid & 1;
  const int ln = lane & 15, quad = lane >> 4;

  const int b    = blockIdx.x;
  const int row0 = (b & 63) * 64;           // XCD-pinning key
  const int col0 = (b >> 6) * 64;

  f32x4 acc[2][2] = {};

  const int lr = lane >> 3;                 // staging row within 8-row inst
  const int cg = (lane & 7) ^ lr;           // XOR-swizzled 16B chunk to fetch

  const unsigned short* aRow = Ag + (size_t)(row0 + wid * 16 + lr) * KDIM + cg * 8;
  const unsigned short* bRow = Wt + (size_t)(col0 + wid * 16 + lr) * KDIM + cg * 8;

  // issue tile kt's 4 async loads into stage st
  auto issue = [&](int kt, int st) {
    const int k0 = kt * 64;
#pragma unroll
    for (int t = 0; t < 2; ++t) {
      const int rbase = wid * 16 + t * 8;                       // wave-uniform
      async_load16(aRow + (size_t)t * 8 * KDIM + k0, &As[st][rbase * 64]);
      async_load16(bRow + (size_t)t * 8 * KDIM + k0, &Bs[st][rbase * 64]);
    }
  };

  auto compute = [&](int st) {
#pragma unroll
    for (int kk = 0; kk < 2; ++kk) {
      short8 af[2], bfr[2];
#pragma unroll
      for (int mt = 0; mt < 2; ++mt) {
        const int r    = wm * 32 + mt * 16 + ln;
        const int slot = (kk * 4 + quad) ^ (r & 7);
        af[mt] = *reinterpret_cast<const short8*>(&As[st][r * 64 + slot * 8]);
      }
#pragma unroll
      for (int nt = 0; nt < 2; ++nt) {
        const int c    = wn * 32 + nt * 16 + ln;
        const int slot = (kk * 4 + quad) ^ (c & 7);
        bfr[nt] = *reinterpret_cast<const short8*>(&Bs[st][c * 64 + slot * 8]);
      }
#pragma unroll
      for (int mt = 0; mt < 2; ++mt)
#pragma unroll
        for (int nt = 0; nt < 2; ++nt)
          acc[mt][nt] = __builtin_amdgcn_mfma_f32_16x16x32_bf16(af[mt], bfr[nt], acc[mt][nt], 0, 0, 0);
    }
  };

  issue(0, 0); issue(1, 1); issue(2, 2);

  int st = 0;
  for (int kt = 0; kt < NKT - 3; ++kt) {
    __builtin_amdgcn_s_waitcnt(WAIT_VM8);
    __builtin_amdgcn_s_barrier();
    compute(st);
    __builtin_amdgcn_s_barrier();
    issue(kt + 3, st);
    st = (st == 2) ? 0 : st + 1;
  }
  // tail: tiles NKT-3, NKT-2, NKT-1 (stages st, st+1, st+2 mod 3)
  __builtin_amdgcn_s_waitcnt(WAIT_VM8);
  __builtin_amdgcn_s_barrier();
  compute(st);
  st = (st == 2) ? 0 : st + 1;
  __builtin_amdgcn_s_waitcnt(WAIT_VM4);
  __builtin_amdgcn_s_barrier();
  compute(st);
  st = (st == 2) ? 0 : st + 1;
  __builtin_amdgcn_s_waitcnt(WAIT_VM0);
  __builtin_amdgcn_s_barrier();
  compute(st);

  // C/D layout: col = lane&15, row = quad*4 + reg
#pragma unroll
  for (int mt = 0; mt < 2; ++mt)
#pragma unroll
    for (int nt = 0; nt < 2; ++nt) {
      const int col = col0 + wn * 32 + nt * 16 + ln;
#pragma unroll
      for (int r = 0; r < 4; ++r) {
        const int row = row0 + wm * 32 + mt * 16 + quad * 4 + r;
        out[(size_t)row * OUT_DIM + col] = acc[mt][nt][r];
      }
    }
}

// ---- fallback (no ws): on-the-fly staging, 64-tile, direct store ---------
__global__ __launch_bounds__(256, 2)
void kan_gemm_fb(const float* __restrict__ x, const float* __restrict__ coeff,
                 const float* __restrict__ scaling, float* __restrict__ out) {
  __shared__ unsigned short As[64 * 64];
  __shared__ unsigned short Bs[64 * 64];

  const int tid  = threadIdx.x;
  const int lane = tid & 63;
  const int wid  = tid >> 6;
  const int wm = wid >> 1, wn = wid & 1;
  const int ln = lane & 15, quad = lane >> 4;
  const int row0 = blockIdx.y * 64;
  const int col0 = blockIdx.x * 64;

  f32x4 acc[2][2] = {};

  for (int kt = 0; kt < KDIM / 64; ++kt) {
#pragma unroll
    for (int pp = 0; pp < 2; ++pp) {
      const int p  = tid + pp * 256;
      const int rn = p & 63;
      const int il = p >> 6;
      const int sw = ((il ^ (rn & 7)) * 8);
      short8 ha = basis_pack8(x[(size_t)(row0 + rn) * IN_DIM + kt * 8 + il]);
      *reinterpret_cast<short8*>(&As[rn * 64 + sw]) = ha;
      const float* cbase = coeff + (size_t)(kt * 8 + il) * 4096 + (size_t)(col0 + rn) * 8;
      float4 c0 = reinterpret_cast<const float4*>(cbase)[0];
      float4 c1 = reinterpret_cast<const float4*>(cbase)[1];
      float s = scaling[(size_t)(kt * 8 + il) * OUT_DIM + col0 + rn];
      short8 hb;
      hb[0] = (short)f2bf(c0.x * s); hb[1] = (short)f2bf(c0.y * s);
      hb[2] = (short)f2bf(c0.z * s); hb[3] = (short)f2bf(c0.w * s);
      hb[4] = (short)f2bf(c1.x * s); hb[5] = (short)f2bf(c1.y * s);
      hb[6] = (short)f2bf(c1.z * s); hb[7] = (short)f2bf(c1.w * s);
      *reinterpret_cast<short8*>(&Bs[rn * 64 + sw]) = hb;
    }
    __syncthreads();
#pragma unroll
    for (int kk = 0; kk < 2; ++kk) {
      short8 af[2], bfr[2];
#pragma unroll
      for (int mt = 0; mt < 2; ++mt) {
        const int r  = wm * 32 + mt * 16 + ln;
        const int pc = (kk * 4 + quad) ^ (r & 7);
        af[mt] = *reinterpret_cast<const short8*>(&As[r * 64 + pc * 8]);
      }
#pragma unroll
      for (int nt = 0; nt < 2; ++nt) {
        const int c  = wn * 32 + nt * 16 + ln;
        const int pc = (kk * 4 + quad) ^ (c & 7);
        bfr[nt] = *reinterpret_cast<const short8*>(&Bs[c * 64 + pc * 8]);
      }
#pragma unroll
      for (int mt = 0; mt < 2; ++mt)
#pragma unroll
        for (int nt = 0; nt < 2; ++nt)
          acc[mt][nt] = __builtin_amdgcn_mfma_f32_16x16x32_bf16(af[mt], bfr[nt], acc[mt][nt], 0, 0, 0);
    }
    __syncthreads();
  }
#pragma unroll
  for (int mt = 0; mt < 2; ++mt)
#pragma unroll
    for (int nt = 0; nt < 2; ++nt) {
      const int col = col0 + wn * 32 + nt * 16 + ln;
#pragma unroll
      for (int r = 0; r < 4; ++r) {
        const int row = row0 + wm * 32 + mt * 16 + quad * 4 + r;
        out[(size_t)row * OUT_DIM + col] = acc[mt][nt][r];
      }
    }
}

// ---- launch ------------------------------------------------------------
extern "C" void kernel_launch(void* const* d_in, const int* in_sizes, int n_in,
                              void* d_out, int out_size, void* d_ws, size_t ws_size,
                              hipStream_t stream) {
  const float* x       = (const float*)d_in[0];
  const float* coeff   = (const float*)d_in[1];
  const float* scaling = (const float*)d_in[2];
  float* out = (float*)d_out;

  const size_t needA = (size_t)BATCH * KDIM * 2;     // 32 MB bf16 basis
  const size_t needW = (size_t)OUT_DIM * KDIM * 2;   // 4 MB bf16 W^T

  if (ws_size >= needA + needW) {
    unsigned short* Ag = (unsigned short*)d_ws;
    unsigned short* Wt = (unsigned short*)((char*)d_ws + needA);
    kan_prep<<<(BATCH * IN_DIM) / 256 + (IN_DIM * OUT_DIM) / 256, 256, 0, stream>>>(
        x, coeff, scaling, Ag, Wt);
    kan_gemm_p<<<(BATCH / 64) * (OUT_DIM / 64), 256, 0, stream>>>(Ag, Wt, out);
  } else {
    kan_gemm_fb<<<dim3(OUT_DIM / 64, BATCH / 64), 256, 0, stream>>>(x, coeff, scaling, out);
  }
}